// Round 2
// baseline (144.129 us; speedup 1.0000x reference)
//
#include <hip/hip_runtime.h>
#include <hip/hip_bf16.h>

#define NS 64
#define DIM 128
#define BATCH_N 16384

typedef float f32x4 __attribute__((ext_vector_type(4)));
typedef _Float16 f16x8 __attribute__((ext_vector_type(8)));
typedef unsigned int u32;
typedef unsigned long long u64;

// fp32 -> fp16 (RNE via hardware cvt)
__device__ __forceinline__ unsigned short f2h(float f) {
    _Float16 h = (_Float16)f;
    return __builtin_bit_cast(unsigned short, h);
}

// ---------------------------------------------------------------------------
// prep 1: build fp16 MFMA A-operand fragments in d_ws.
// Layout: frag[s][t][kk][mm][lane][j] ; t=0 -> A0, t=1 -> D = A1-A0
// value = M[kk*32 + (lane>>4)*8 + j][mm*16 + (lane&15)]
// total threads = 64*2*4*8*64 = 262144  -> <<<1024, 256>>>
// ---------------------------------------------------------------------------
__global__ void prep_frags(const float* __restrict__ data,
                           unsigned short* __restrict__ afrag) {
    int idx = blockIdx.x * blockDim.x + threadIdx.x;
    if (idx >= 64 * 2 * 4 * 8 * 64) return;
    int l  = idx & 63;
    int mm = (idx >> 6) & 7;
    int kk = (idx >> 9) & 3;
    int t  = (idx >> 11) & 1;
    int s  = idx >> 12;
    int m = mm * 16 + (l & 15);
    int kbase = kk * 32 + (l >> 4) * 8;
    const float* a0 = data + ((size_t)s * 2 + 0) * DIM * DIM;
    const float* a1 = a0 + DIM * DIM;
    unsigned short outv[8];
#pragma unroll
    for (int j = 0; j < 8; ++j) {
        int k = kbase + j;
        float v0 = a0[k * DIM + m];
        float vv = (t == 0) ? v0 : (a1[k * DIM + m] - v0);
        outv[j] = f2h(vv);
    }
    *reinterpret_cast<uint4*>(afrag + (size_t)idx * 8) =
        *reinterpret_cast<uint4*>(outv);
}

// ---------------------------------------------------------------------------
// prep 2: pack occupation bits, one u64 per batch row (bit t = onstate[r][image2[t]])
// ---------------------------------------------------------------------------
__global__ void prep_bits(const int* __restrict__ onstate,
                          const int* __restrict__ image2,
                          u64* __restrict__ bits) {
    int r = blockIdx.x * blockDim.x + threadIdx.x;
    if (r >= BATCH_N) return;
    const int* row = onstate + (size_t)r * NS;
    u64 b = 0;
#pragma unroll 8
    for (int t = 0; t < NS; ++t) {
        b |= ((u64)(row[image2[t]] & 1)) << t;
    }
    bits[r] = b;
}

// ---------------------------------------------------------------------------
// main: 256 blocks x 256 threads; block owns 64 batch rows through all sites.
// wave w computes m-blocks {2w, 2w+1}; v exchanged via swizzled LDS dbuf.
// ---------------------------------------------------------------------------
__global__ __launch_bounds__(256, 1)
void mps_main(const unsigned short* __restrict__ afrag,
              const u64* __restrict__ occbits,
              const float* __restrict__ left,
              const float* __restrict__ right,
              float* __restrict__ out) {
    __shared__ unsigned short vlds[2][64 * DIM];   // 2 x 16 KB, fp16 v, swizzled
    __shared__ float red[64][17];                  // final reduction scratch

    const int tid  = threadIdx.x;
    const int wid  = tid >> 6;
    const int lane = tid & 63;
    const int li   = lane & 15;
    const int g    = lane >> 4;
    const int rbase = blockIdx.x * 64;
    const int mmb  = wid * 2;

    // occupation bits for this lane's 4 rows
    u64 bits[4];
#pragma unroll
    for (int rg = 0; rg < 4; ++rg)
        bits[rg] = occbits[rbase + rg * 16 + li];

    // init v buffer 0 with fp16(left), swizzled: byte(r,b) = r*256 + b ^ ((r&7)<<4)
    for (int c = tid; c < 64 * 16; c += 256) {
        int r  = c >> 4;
        int kc = c & 15;
        unsigned short tmp[8];
#pragma unroll
        for (int j = 0; j < 8; ++j) tmp[j] = f2h(left[kc * 8 + j]);
        u32 byte = (u32)(r * 256 + kc * 16) ^ ((u32)(r & 7) << 4);
        *reinterpret_cast<uint4*>(reinterpret_cast<char*>(&vlds[0][0]) + byte) =
            *reinterpret_cast<uint4*>(tmp);
    }
    __syncthreads();

    const f16x8 zf = {0, 0, 0, 0, 0, 0, 0, 0};
    f32x4 acc[4][2];

    for (int s = 0; s < NS; ++s) {
        const char* vb = reinterpret_cast<const char*>(&vlds[s & 1][0]);
        char*       wb = reinterpret_cast<char*>(&vlds[(s + 1) & 1][0]);

#pragma unroll
        for (int rg = 0; rg < 4; ++rg)
#pragma unroll
            for (int m2 = 0; m2 < 2; ++m2)
                acc[rg][m2] = (f32x4){0.f, 0.f, 0.f, 0.f};

        // B-fragments (v^T) from LDS: lane reads v[rg*16+li][kk*32 + g*8 .. +7]
        f16x8 bfr[4][4];   // [rg][kk]
#pragma unroll
        for (int kk = 0; kk < 4; ++kk)
#pragma unroll
            for (int rg = 0; rg < 4; ++rg) {
                int r = rg * 16 + li;
                u32 byte = (u32)(r * 256 + kk * 64 + g * 16) ^ ((u32)(r & 7) << 4);
                bfr[rg][kk] = *reinterpret_cast<const f16x8*>(vb + byte);
            }

        // A-fragments (matrix) straight from global (L2-resident)
        f16x8 fa[4][2], fd[4][2];   // [kk][m2]
        const unsigned short* sb = afrag + (size_t)s * 32768;
#pragma unroll
        for (int kk = 0; kk < 4; ++kk)
#pragma unroll
            for (int m2 = 0; m2 < 2; ++m2) {
                fa[kk][m2] = *reinterpret_cast<const f16x8*>(
                    sb + ((0 * 4 + kk) * 8 + mmb + m2) * 512 + lane * 8);
                fd[kk][m2] = *reinterpret_cast<const f16x8*>(
                    sb + ((1 * 4 + kk) * 8 + mmb + m2) * 512 + lane * 8);
            }

        // MFMA: acc[rg][m2] += A0^T(kk,mm) * v(rg,kk)  +  D^T(kk,mm) * (v*n)(rg,kk)
#pragma unroll
        for (int kk = 0; kk < 4; ++kk) {
#pragma unroll
            for (int rg = 0; rg < 4; ++rg) {
                bool mk = (bits[rg] >> s) & 1;
                f16x8 mb = mk ? bfr[rg][kk] : zf;
#pragma unroll
                for (int m2 = 0; m2 < 2; ++m2) {
                    acc[rg][m2] = __builtin_amdgcn_mfma_f32_16x16x32_f16(
                        fa[kk][m2], bfr[rg][kk], acc[rg][m2], 0, 0, 0);
                    acc[rg][m2] = __builtin_amdgcn_mfma_f32_16x16x32_f16(
                        fd[kk][m2], mb, acc[rg][m2], 0, 0, 0);
                }
            }
        }

        if (s < NS - 1) {
            // write v_new (fp16) into the other buffer.
            // lane holds v_new[m = (mmb+m2)*16 + g*4 + j][r = rg*16 + li]
#pragma unroll
            for (int rg = 0; rg < 4; ++rg) {
                int r = rg * 16 + li;
#pragma unroll
                for (int m2 = 0; m2 < 2; ++m2) {
                    int mbase = (mmb + m2) * 16 + g * 4;
                    u32 lo = ((u32)f2h(acc[rg][m2][1]) << 16) | f2h(acc[rg][m2][0]);
                    u32 hi = ((u32)f2h(acc[rg][m2][3]) << 16) | f2h(acc[rg][m2][2]);
                    u32 byte = (u32)(r * 256 + mbase * 2) ^ ((u32)(r & 7) << 4);
                    uint2 w = {lo, hi};
                    *reinterpret_cast<uint2*>(wb + byte) = w;
                }
            }
            __syncthreads();
        } else {
            // final: out[r] = sum_m v[r][m] * right[m]
#pragma unroll
            for (int rg = 0; rg < 4; ++rg) {
                float p = 0.f;
#pragma unroll
                for (int m2 = 0; m2 < 2; ++m2) {
                    int mbase = (mmb + m2) * 16 + g * 4;
                    const float4 rv = *reinterpret_cast<const float4*>(right + mbase);
                    p += acc[rg][m2][0] * rv.x + acc[rg][m2][1] * rv.y +
                         acc[rg][m2][2] * rv.z + acc[rg][m2][3] * rv.w;
                }
                red[rg * 16 + li][wid * 4 + g] = p;
            }
            __syncthreads();
            if (tid < 64) {
                float ssum = 0.f;
#pragma unroll
                for (int i = 0; i < 16; ++i) ssum += red[tid][i];
                out[rbase + tid] = ssum;
            }
        }
    }
}

// ---------------------------------------------------------------------------
extern "C" void kernel_launch(void* const* d_in, const int* in_sizes, int n_in,
                              void* d_out, int out_size, void* d_ws, size_t ws_size,
                              hipStream_t stream) {
    const int*   onstate = (const int*)d_in[0];
    const float* data    = (const float*)d_in[1];
    const float* left    = (const float*)d_in[2];
    const float* right   = (const float*)d_in[3];
    const int*   image2  = (const int*)d_in[4];
    float* out = (float*)d_out;

    unsigned short* afrag = (unsigned short*)d_ws;                       // 4 MB
    u64* bits = (u64*)((char*)d_ws + (size_t)2097152 * sizeof(unsigned short));

    prep_frags<<<1024, 256, 0, stream>>>(data, afrag);   // 262144 threads
    prep_bits<<<64, 256, 0, stream>>>(onstate, image2, bits);
    mps_main<<<256, 256, 0, stream>>>(afrag, bits, left, right, out);
}

// Round 3
// 103.925 us; speedup vs baseline: 1.3869x; 1.3869x over previous
//
#include <hip/hip_runtime.h>
#include <hip/hip_bf16.h>

#define NS 64
#define DIM 128
#define BATCH_N 16384

typedef float f32x4 __attribute__((ext_vector_type(4)));
typedef _Float16 f16x8 __attribute__((ext_vector_type(8)));
typedef unsigned int u32;
typedef unsigned long long u64;

// fp32 -> fp16 (RNE via hardware cvt)
__device__ __forceinline__ unsigned short f2h(float f) {
    _Float16 h = (_Float16)f;
    return __builtin_bit_cast(unsigned short, h);
}

// ---------------------------------------------------------------------------
// prep 1: build fp16 MFMA A-operand fragments in d_ws.
// Layout: frag[s][t][kk][mm][lane][j] ; t=0 -> A0, t=1 -> D = A1-A0
// value = M[kk*32 + (lane>>4)*8 + j][mm*16 + (lane&15)]
// ---------------------------------------------------------------------------
__global__ void prep_frags(const float* __restrict__ data,
                           unsigned short* __restrict__ afrag) {
    int idx = blockIdx.x * blockDim.x + threadIdx.x;
    if (idx >= 64 * 2 * 4 * 8 * 64) return;
    int l  = idx & 63;
    int mm = (idx >> 6) & 7;
    int kk = (idx >> 9) & 3;
    int t  = (idx >> 11) & 1;
    int s  = idx >> 12;
    int m = mm * 16 + (l & 15);
    int kbase = kk * 32 + (l >> 4) * 8;
    const float* a0 = data + ((size_t)s * 2 + 0) * DIM * DIM;
    const float* a1 = a0 + DIM * DIM;
    unsigned short outv[8];
#pragma unroll
    for (int j = 0; j < 8; ++j) {
        int k = kbase + j;
        float v0 = a0[k * DIM + m];
        float vv = (t == 0) ? v0 : (a1[k * DIM + m] - v0);
        outv[j] = f2h(vv);
    }
    *reinterpret_cast<uint4*>(afrag + (size_t)idx * 8) =
        *reinterpret_cast<uint4*>(outv);
}

// ---------------------------------------------------------------------------
// prep 2: pack occupation bits, one u64 per batch row
// ---------------------------------------------------------------------------
__global__ void prep_bits(const int* __restrict__ onstate,
                          const int* __restrict__ image2,
                          u64* __restrict__ bits) {
    int r = blockIdx.x * blockDim.x + threadIdx.x;
    if (r >= BATCH_N) return;
    const int* row = onstate + (size_t)r * NS;
    u64 b = 0;
#pragma unroll 8
    for (int t = 0; t < NS; ++t) {
        b |= ((u64)(row[image2[t]] & 1)) << t;
    }
    bits[r] = b;
}

// ---------------------------------------------------------------------------
// main: 256 blocks x 512 threads (8 waves, 2/SIMD); block owns 64 batch rows.
// wave w computes m-block w (16 dims); v exchanged via swizzled LDS dbuf.
// A-fragments double-buffered in registers across sites (prefetch s+1 while
// computing s) so L2 latency hides under MFMA.
// ---------------------------------------------------------------------------
__global__ __launch_bounds__(512, 2)
void mps_main(const unsigned short* __restrict__ afrag,
              const u64* __restrict__ occbits,
              const float* __restrict__ left,
              const float* __restrict__ right,
              float* __restrict__ out) {
    __shared__ unsigned short vlds[2][64 * DIM];   // 2 x 16 KB, fp16 v, swizzled
    __shared__ float red[64][33];                  // final reduction scratch

    const int tid  = threadIdx.x;
    const int wid  = tid >> 6;          // 0..7 -> m-block
    const int lane = tid & 63;
    const int li   = lane & 15;
    const int g    = lane >> 4;
    const int rbase = blockIdx.x * 64;

    // occupation bits for this lane's 4 rows
    u64 bits[4];
#pragma unroll
    for (int rg = 0; rg < 4; ++rg)
        bits[rg] = occbits[rbase + rg * 16 + li];

    // init v buffer 0 with fp16(left), swizzled: byte(r,b) = (r*256 + b) ^ ((r&7)<<4)
    for (int c = tid; c < 64 * 16; c += 512) {
        int r  = c >> 4;
        int kc = c & 15;
        unsigned short tmp[8];
#pragma unroll
        for (int j = 0; j < 8; ++j) tmp[j] = f2h(left[kc * 8 + j]);
        u32 byte = (u32)(r * 256 + kc * 16) ^ ((u32)(r & 7) << 4);
        *reinterpret_cast<uint4*>(reinterpret_cast<char*>(&vlds[0][0]) + byte) =
            *reinterpret_cast<uint4*>(tmp);
    }
    __syncthreads();

    const f16x8 zf = {0, 0, 0, 0, 0, 0, 0, 0};

    f16x8 fa0[4], fd0[4], fa1[4], fd1[4];   // A-frag double buffer (per-kk)

#define ISSUE(FA, FD, S_)                                                     \
    {                                                                         \
        const unsigned short* sb_ = afrag + (size_t)(S_) * 32768;             \
        _Pragma("unroll")                                                     \
        for (int kk = 0; kk < 4; ++kk) {                                      \
            FA[kk] = *reinterpret_cast<const f16x8*>(                         \
                sb_ + ((size_t)((0 * 4 + kk) * 8 + wid) * 512) + lane * 8);   \
            FD[kk] = *reinterpret_cast<const f16x8*>(                         \
                sb_ + ((size_t)((1 * 4 + kk) * 8 + wid) * 512) + lane * 8);   \
        }                                                                     \
    }

#define COMPUTE(S_, FA, FD)                                                   \
    {                                                                         \
        const int s_ = (S_);                                                  \
        const char* vb = reinterpret_cast<const char*>(&vlds[s_ & 1][0]);     \
        char*       wb = reinterpret_cast<char*>(&vlds[(s_ + 1) & 1][0]);     \
        f32x4 acc[4];                                                         \
        _Pragma("unroll")                                                     \
        for (int rg = 0; rg < 4; ++rg) acc[rg] = (f32x4){0.f, 0.f, 0.f, 0.f}; \
        f16x8 bfr[4][4];                                                      \
        _Pragma("unroll")                                                     \
        for (int kk = 0; kk < 4; ++kk)                                        \
            _Pragma("unroll")                                                 \
            for (int rg = 0; rg < 4; ++rg) {                                  \
                int r = rg * 16 + li;                                         \
                u32 byte = (u32)(r * 256 + kk * 64 + g * 16) ^                \
                           ((u32)(r & 7) << 4);                               \
                bfr[rg][kk] = *reinterpret_cast<const f16x8*>(vb + byte);     \
            }                                                                 \
        _Pragma("unroll")                                                     \
        for (int kk = 0; kk < 4; ++kk) {                                      \
            _Pragma("unroll")                                                 \
            for (int rg = 0; rg < 4; ++rg) {                                  \
                bool mk = (bits[rg] >> s_) & 1;                               \
                f16x8 mb = mk ? bfr[rg][kk] : zf;                             \
                acc[rg] = __builtin_amdgcn_mfma_f32_16x16x32_f16(             \
                    FA[kk], bfr[rg][kk], acc[rg], 0, 0, 0);                   \
                acc[rg] = __builtin_amdgcn_mfma_f32_16x16x32_f16(             \
                    FD[kk], mb, acc[rg], 0, 0, 0);                            \
            }                                                                 \
        }                                                                     \
        if (s_ < NS - 1) {                                                    \
            _Pragma("unroll")                                                 \
            for (int rg = 0; rg < 4; ++rg) {                                  \
                int r = rg * 16 + li;                                         \
                int mbase = wid * 16 + g * 4;                                 \
                u32 lo = ((u32)f2h(acc[rg][1]) << 16) | f2h(acc[rg][0]);      \
                u32 hi = ((u32)f2h(acc[rg][3]) << 16) | f2h(acc[rg][2]);      \
                u32 byte = (u32)(r * 256 + mbase * 2) ^ ((u32)(r & 7) << 4);  \
                uint2 w = {lo, hi};                                           \
                *reinterpret_cast<uint2*>(wb + byte) = w;                     \
            }                                                                 \
            __syncthreads();                                                  \
        } else {                                                              \
            _Pragma("unroll")                                                 \
            for (int rg = 0; rg < 4; ++rg) {                                  \
                int mbase = wid * 16 + g * 4;                                 \
                const float4 rv =                                             \
                    *reinterpret_cast<const float4*>(right + mbase);          \
                float p = acc[rg][0] * rv.x + acc[rg][1] * rv.y +             \
                          acc[rg][2] * rv.z + acc[rg][3] * rv.w;              \
                red[rg * 16 + li][wid * 4 + g] = p;                           \
            }                                                                 \
            __syncthreads();                                                  \
            if (tid < 64) {                                                   \
                float ssum = 0.f;                                             \
                _Pragma("unroll")                                             \
                for (int i = 0; i < 32; ++i) ssum += red[tid][i];             \
                out[rbase + tid] = ssum;                                      \
            }                                                                 \
        }                                                                     \
    }

    ISSUE(fa0, fd0, 0);
    for (int sp = 0; sp < NS; sp += 2) {
        ISSUE(fa1, fd1, sp + 1);        // prefetch odd site (issued early,
        COMPUTE(sp, fa0, fd0);          //  latency hides under these MFMAs)
        if (sp + 2 < NS) ISSUE(fa0, fd0, sp + 2);   // prefetch next even site
        COMPUTE(sp + 1, fa1, fd1);
    }

#undef ISSUE
#undef COMPUTE
}

// ---------------------------------------------------------------------------
extern "C" void kernel_launch(void* const* d_in, const int* in_sizes, int n_in,
                              void* d_out, int out_size, void* d_ws, size_t ws_size,
                              hipStream_t stream) {
    const int*   onstate = (const int*)d_in[0];
    const float* data    = (const float*)d_in[1];
    const float* left    = (const float*)d_in[2];
    const float* right   = (const float*)d_in[3];
    const int*   image2  = (const int*)d_in[4];
    float* out = (float*)d_out;

    unsigned short* afrag = (unsigned short*)d_ws;                       // 4 MB
    u64* bits = (u64*)((char*)d_ws + (size_t)2097152 * sizeof(unsigned short));

    prep_frags<<<1024, 256, 0, stream>>>(data, afrag);   // 262144 threads
    prep_bits<<<64, 256, 0, stream>>>(onstate, image2, bits);
    mps_main<<<256, 512, 0, stream>>>(afrag, bits, left, right, out);
}